// Round 1
// baseline (22050.723 us; speedup 1.0000x reference)
//
#include <hip/hip_runtime.h>
#include <hip/hip_bf16.h>
#include <math.h>

// LSTM decoder: B=64, T=512, IN=256, OUT=256, H=1024, 2 layers + linear head.
// Strategy (round 1): per-step kernel pair (layer0-cell, layer1-cell+deferred
// projection), bf16 MFMA 16x16x32 with fp32 accumulation, fp32 cell state.
// Weights reordered gate-interleaved (row = unit*4 + gate) so each 16-col
// block owns complete units and can apply the LSTM cell in its epilogue.
// Projection of h1[t-1] is computed as 256 extra columns of the step-t layer1
// GEMM (zero-padded K for the h0 half); final step projected by k_proj_last.

typedef __attribute__((ext_vector_type(8))) short bf16x8;   // 8 x bf16 (4 VGPRs)
typedef __attribute__((ext_vector_type(4))) float f32x4;

#define H1OFF ((size_t)65536)   // 64*1024 elements per h buffer

// ---------------- prep kernels (one-time per launch) ----------------

// W0cat[u*4+g][k] : k<256 -> Wih0[g*1024+u][k], else Whh0[g*1024+u][k-256]
__global__ __launch_bounds__(256) void prep_w0(const float* __restrict__ Wih0,
                                               const float* __restrict__ Whh0,
                                               __hip_bfloat16* __restrict__ W0) {
  const unsigned n = 4096u * 1280u;
  for (unsigned d = blockIdx.x * blockDim.x + threadIdx.x; d < n;
       d += blockDim.x * gridDim.x) {
    unsigned r = d / 1280u;
    unsigned k = d - r * 1280u;
    unsigned u = r >> 2, g = r & 3u;
    unsigned srow = g * 1024u + u;
    float v = (k < 256u) ? Wih0[(size_t)srow * 256u + k]
                         : Whh0[(size_t)srow * 1024u + (k - 256u)];
    W0[d] = __float2bfloat16(v);
  }
}

// W1ext[4352][2048]: rows<4096 reordered LSTM1 weights [Wih1|Whh1];
// rows 4096+o: [zeros(1024) | Wlin[o]]  (projection uses the h1 half of A)
__global__ __launch_bounds__(256) void prep_w1(const float* __restrict__ Wih1,
                                               const float* __restrict__ Whh1,
                                               const float* __restrict__ Wlin,
                                               __hip_bfloat16* __restrict__ W1) {
  const unsigned n = 4352u * 2048u;
  for (unsigned d = blockIdx.x * blockDim.x + threadIdx.x; d < n;
       d += blockDim.x * gridDim.x) {
    unsigned r = d >> 11;
    unsigned k = d & 2047u;
    float v;
    if (r < 4096u) {
      unsigned u = r >> 2, g = r & 3u;
      unsigned srow = g * 1024u + u;
      v = (k < 1024u) ? Wih1[(size_t)srow * 1024u + k]
                      : Whh1[(size_t)srow * 1024u + (k - 1024u)];
    } else {
      unsigned o = r - 4096u;
      v = (k < 1024u) ? 0.f : Wlin[(size_t)o * 1024u + (k - 1024u)];
    }
    W1[d] = __float2bfloat16(v);
  }
}

// xbf[t][b][k] = bf16( t==0 ? 0 : x[b][t-1][k] )   (teacher forcing shift)
__global__ __launch_bounds__(256) void prep_x(const float* __restrict__ x,
                                              __hip_bfloat16* __restrict__ xbf) {
  const unsigned n = 512u * 64u * 256u;
  for (unsigned d = blockIdx.x * blockDim.x + threadIdx.x; d < n;
       d += blockDim.x * gridDim.x) {
    unsigned t = d >> 14;          // /(64*256)
    unsigned b = (d >> 8) & 63u;
    unsigned k = d & 255u;
    float v = (t == 0u) ? 0.f : x[((size_t)b * 512u + (t - 1u)) * 256u + k];
    xbf[d] = __float2bfloat16(v);
  }
}

// biases (gate-interleaved, bih+bhh combined) + state init (h=z, c=0)
__global__ __launch_bounds__(256) void prep_misc(
    const float* __restrict__ bih0, const float* __restrict__ bhh0,
    const float* __restrict__ bih1, const float* __restrict__ bhh1,
    const float* __restrict__ z, float* __restrict__ b0, float* __restrict__ b1,
    __hip_bfloat16* __restrict__ h0buf, __hip_bfloat16* __restrict__ h1buf,
    float* __restrict__ c0, float* __restrict__ c1) {
  for (int i = blockIdx.x * blockDim.x + threadIdx.x; i < 73728;
       i += blockDim.x * gridDim.x) {
    if (i < 4096) {
      int u = i >> 2, g = i & 3;
      b0[i] = bih0[g * 1024 + u] + bhh0[g * 1024 + u];
    } else if (i < 8192) {
      int r = i - 4096;
      int u = r >> 2, g = r & 3;
      b1[r] = bih1[g * 1024 + u] + bhh1[g * 1024 + u];
    } else {
      int j = i - 8192;  // 0..65535
      __hip_bfloat16 hb = __float2bfloat16(z[j]);
      h0buf[j] = hb;
      h1buf[j] = hb;
      c0[j] = 0.f;
      c1[j] = 0.f;
    }
  }
}

// ---------------- per-step kernels ----------------
// Block: 512 threads = 8 waves = 4 M-strips x 2 K-halves; block owns 16 cols.
// MFMA frags (m89-verified layouts):
//   A[m=lane&15][k=(lane>>4)*8+j]  -> contiguous 16B row segment
//   B[k=(lane>>4)*8+j][n=lane&15]  -> contiguous 16B of W row n
//   C/D: col=lane&15, row=(lane>>4)*4+reg

__device__ __forceinline__ float sigm(float v) { return 1.f / (1.f + expf(-v)); }

__global__ __launch_bounds__(512) void k_l0(
    const __hip_bfloat16* __restrict__ xbf, const __hip_bfloat16* __restrict__ W0,
    const float* __restrict__ b0, __hip_bfloat16* __restrict__ h0buf,
    float* __restrict__ c0, int t) {
  const int tid = threadIdx.x;
  const int lane = tid & 63;
  const int wave = tid >> 6;
  const int mstrip = wave & 3;
  const int khalf = wave >> 2;
  const int cb = blockIdx.x << 4;                 // column base (reordered gates)
  const int m = (mstrip << 4) + (lane & 15);      // batch row for A frag
  const int kq = lane >> 4;                       // k-quad
  const int n = cb + (lane & 15);                 // weight row for B frag

  const __hip_bfloat16* xrow =
      xbf + (((size_t)t << 6) + (size_t)m) * 256 + (kq << 3);
  const __hip_bfloat16* hrow =
      h0buf + ((size_t)(t & 1) << 16) + ((size_t)m << 10) + (kq << 3);
  const __hip_bfloat16* wrow = W0 + (size_t)n * 1280 + (kq << 3);

  f32x4 acc = {0.f, 0.f, 0.f, 0.f};
  const int kbeg = khalf * 640;                   // K=1280 split in halves
#pragma unroll 4
  for (int k0 = kbeg; k0 < kbeg + 640; k0 += 32) {
    bf16x8 a = (k0 < 256) ? *(const bf16x8*)(xrow + k0)
                          : *(const bf16x8*)(hrow + (k0 - 256));
    bf16x8 b = *(const bf16x8*)(wrow + k0);
    acc = __builtin_amdgcn_mfma_f32_16x16x32_bf16(a, b, acc, 0, 0, 0);
  }

  __shared__ float Cl[16][65];                    // [col][row(b)], +1 pad
  if (khalf == 0) {
#pragma unroll
    for (int r = 0; r < 4; ++r)
      Cl[lane & 15][(mstrip << 4) + (kq << 2) + r] = acc[r];
  }
  __syncthreads();
  if (khalf == 1) {
#pragma unroll
    for (int r = 0; r < 4; ++r)
      Cl[lane & 15][(mstrip << 4) + (kq << 2) + r] += acc[r];
  }
  __syncthreads();

  if (tid < 256) {                                // 4 units x 64 batch
    const int u_l = tid & 3;
    const int b_ = tid >> 2;
    const int cc = u_l << 2;
    float gi = Cl[cc + 0][b_] + b0[cb + cc + 0];
    float gf = Cl[cc + 1][b_] + b0[cb + cc + 1];
    float gg = Cl[cc + 2][b_] + b0[cb + cc + 2];
    float go = Cl[cc + 3][b_] + b0[cb + cc + 3];
    const int u = (cb >> 2) + u_l;
    const int su = (b_ << 10) + u;
    float cn = sigm(gf) * c0[su] + sigm(gi) * tanhf(gg);
    c0[su] = cn;
    float hn = sigm(go) * tanhf(cn);
    h0buf[((size_t)((t + 1) & 1) << 16) + su] = __float2bfloat16(hn);
  }
}

__global__ __launch_bounds__(512) void k_l1(
    const __hip_bfloat16* __restrict__ h0buf, const __hip_bfloat16* __restrict__ W1,
    const float* __restrict__ b1, const float* __restrict__ blin,
    __hip_bfloat16* __restrict__ h1buf, float* __restrict__ c1,
    float* __restrict__ out, int t) {
  const int cb = blockIdx.x << 4;                 // 0..4351
  const bool isproj = (cb >= 4096);
  if (isproj && t == 0) return;                   // proj of h1[-1] not needed
  const int tid = threadIdx.x;
  const int lane = tid & 63;
  const int wave = tid >> 6;
  const int mstrip = wave & 3;
  const int khalf = wave >> 2;
  const int m = (mstrip << 4) + (lane & 15);
  const int kq = lane >> 4;
  const int n = cb + (lane & 15);

  const __hip_bfloat16* h0row =
      h0buf + ((size_t)((t + 1) & 1) << 16) + ((size_t)m << 10) + (kq << 3);
  const __hip_bfloat16* h1row =
      h1buf + ((size_t)(t & 1) << 16) + ((size_t)m << 10) + (kq << 3);
  const __hip_bfloat16* wrow = W1 + ((size_t)n << 11) + (kq << 3);

  f32x4 acc = {0.f, 0.f, 0.f, 0.f};
  const int kbeg = khalf << 10;                   // K=2048: half0=h0', half1=h1
  const __hip_bfloat16* arow = khalf ? (h1row - 1024) : h0row;
#pragma unroll 4
  for (int k0 = kbeg; k0 < kbeg + 1024; k0 += 32) {
    bf16x8 a = *(const bf16x8*)(arow + k0);
    bf16x8 b = *(const bf16x8*)(wrow + k0);
    acc = __builtin_amdgcn_mfma_f32_16x16x32_bf16(a, b, acc, 0, 0, 0);
  }

  __shared__ float Cl[16][65];
  if (khalf == 0) {
#pragma unroll
    for (int r = 0; r < 4; ++r)
      Cl[lane & 15][(mstrip << 4) + (kq << 2) + r] = acc[r];
  }
  __syncthreads();
  if (khalf == 1) {
#pragma unroll
    for (int r = 0; r < 4; ++r)
      Cl[lane & 15][(mstrip << 4) + (kq << 2) + r] += acc[r];
  }
  __syncthreads();

  if (!isproj) {
    if (tid < 256) {
      const int u_l = tid & 3;
      const int b_ = tid >> 2;
      const int cc = u_l << 2;
      float gi = Cl[cc + 0][b_] + b1[cb + cc + 0];
      float gf = Cl[cc + 1][b_] + b1[cb + cc + 1];
      float gg = Cl[cc + 2][b_] + b1[cb + cc + 2];
      float go = Cl[cc + 3][b_] + b1[cb + cc + 3];
      const int u = (cb >> 2) + u_l;
      const int su = (b_ << 10) + u;
      float cn = sigm(gf) * c1[su] + sigm(gi) * tanhf(gg);
      c1[su] = cn;
      float hn = sigm(go) * tanhf(cn);
      h1buf[((size_t)((t + 1) & 1) << 16) + su] = __float2bfloat16(hn);
    }
  } else {
    // out[:, t-1, :] = h1[t-1] @ Wlin^T + blin  (h1[t-1] was A's second half)
    for (int idx = tid; idx < 1024; idx += 512) {
      int o_l = idx & 15;
      int b_ = idx >> 4;
      int o = (cb - 4096) + o_l;
      out[(((size_t)b_ << 9) + (size_t)(t - 1)) * 256 + o] = Cl[o_l][b_] + blin[o];
    }
  }
}

// out[:, 511, :] = h1[511] @ Wlin^T + blin ; h1[511] is h1buf parity 0
__global__ __launch_bounds__(256) void k_proj_last(
    const __hip_bfloat16* __restrict__ h1last, const __hip_bfloat16* __restrict__ W1,
    const float* __restrict__ blin, float* __restrict__ out) {
  const int tid = threadIdx.x;
  const int lane = tid & 63;
  const int wave = tid >> 6;                      // M-strip
  const int cb = blockIdx.x << 4;                 // 0..255
  const int m = (wave << 4) + (lane & 15);
  const int kq = lane >> 4;
  const int n = 4096 + cb + (lane & 15);
  const __hip_bfloat16* hrow = h1last + ((size_t)m << 10) + (kq << 3);
  const __hip_bfloat16* wrow = W1 + ((size_t)n << 11) + 1024 + (kq << 3);
  f32x4 acc = {0.f, 0.f, 0.f, 0.f};
#pragma unroll 4
  for (int k0 = 0; k0 < 1024; k0 += 32) {
    bf16x8 a = *(const bf16x8*)(hrow + k0);
    bf16x8 b = *(const bf16x8*)(wrow + k0);
    acc = __builtin_amdgcn_mfma_f32_16x16x32_bf16(a, b, acc, 0, 0, 0);
  }
  __shared__ float Cl[16][65];
#pragma unroll
  for (int r = 0; r < 4; ++r)
    Cl[lane & 15][(wave << 4) + (kq << 2) + r] = acc[r];
  __syncthreads();
  for (int idx = tid; idx < 1024; idx += 256) {
    int o_l = idx & 15;
    int b_ = idx >> 4;
    int o = cb + o_l;
    out[(((size_t)b_ << 9) + 511) * 256 + o] = Cl[o_l][b_] + blin[o];
  }
}

// ---------------- host launch ----------------

extern "C" void kernel_launch(void* const* d_in, const int* in_sizes, int n_in,
                              void* d_out, int out_size, void* d_ws, size_t ws_size,
                              hipStream_t stream) {
  const float* z = (const float*)d_in[0];
  const float* x = (const float*)d_in[1];
  const float* Wih0 = (const float*)d_in[2];
  const float* Whh0 = (const float*)d_in[3];
  const float* bih0 = (const float*)d_in[4];
  const float* bhh0 = (const float*)d_in[5];
  const float* Wih1 = (const float*)d_in[6];
  const float* Whh1 = (const float*)d_in[7];
  const float* bih1 = (const float*)d_in[8];
  const float* bhh1 = (const float*)d_in[9];
  const float* Wlin = (const float*)d_in[10];
  const float* blin = (const float*)d_in[11];
  float* out = (float*)d_out;

  // workspace carve (total 46,170,112 bytes; all offsets 256B-aligned-ish, 16B ok)
  char* ws = (char*)d_ws;
  __hip_bfloat16* W0 = (__hip_bfloat16*)(ws);                   // 4096*1280*2 = 10485760
  __hip_bfloat16* W1 = (__hip_bfloat16*)(ws + 10485760);        // 4352*2048*2 = 17825792
  __hip_bfloat16* xbf = (__hip_bfloat16*)(ws + 28311552);       // 512*64*256*2 = 16777216
  float* b0 = (float*)(ws + 45088768);                          // 16384
  float* b1 = (float*)(ws + 45105152);                          // 16384
  __hip_bfloat16* h0buf = (__hip_bfloat16*)(ws + 45121536);     // 2*64*1024*2 = 262144
  __hip_bfloat16* h1buf = (__hip_bfloat16*)(ws + 45383680);     // 262144
  float* c0 = (float*)(ws + 45645824);                          // 262144
  float* c1 = (float*)(ws + 45907968);                          // 262144

  prep_w0<<<4096, 256, 0, stream>>>(Wih0, Whh0, W0);
  prep_w1<<<4096, 256, 0, stream>>>(Wih1, Whh1, Wlin, W1);
  prep_x<<<4096, 256, 0, stream>>>(x, xbf);
  prep_misc<<<288, 256, 0, stream>>>(bih0, bhh0, bih1, bhh1, z, b0, b1, h0buf,
                                     h1buf, c0, c1);

  for (int t = 0; t < 512; ++t) {
    k_l0<<<256, 512, 0, stream>>>(xbf, W0, b0, h0buf, c0, t);
    k_l1<<<272, 512, 0, stream>>>(h0buf, W1, b1, blin, h1buf, c1, out, t);
  }
  k_proj_last<<<16, 256, 0, stream>>>(h1buf, W1, blin, out);
}